// Round 1
// baseline (2450.928 us; speedup 1.0000x reference)
//
#include <hip/hip_runtime.h>
#include <cstdint>
#include <cstddef>

static inline int ceil_div(int a, int b){ return (a + b - 1) / b; }

// ---------------- dtype detection (int64 vs int32 edge_index) ----------------
__global__ __launch_bounds__(256) void k_detect(const int* __restrict__ ei32, int E, int* __restrict__ flag){
  int t = blockIdx.x * 256 + threadIdx.x;
  if (t < 4096) {
    long long idx = 2LL * t + 1;
    if (idx < 2LL * E && ei32[idx] != 0) atomicOr(flag, 1);
  }
}

// ---------------- CSR build ----------------
__global__ __launch_bounds__(256) void k_count(const void* __restrict__ ei, int E,
                                               const int* __restrict__ flag, int* __restrict__ cnt){
  int e = blockIdx.x * 256 + threadIdx.x;
  if (e >= E) return;
  int dst = (*flag) ? ((const int*)ei)[(size_t)E + e]
                    : (int)((const long long*)ei)[(size_t)E + e];
  atomicAdd(&cnt[dst], 1);
}

__global__ __launch_bounds__(1024) void k_scan(const int* __restrict__ cnt, int* __restrict__ row_ptr, int N){
  __shared__ int sums[1024];
  int t = threadIdx.x;
  int chunk = (N + 1023) >> 10;
  int lo = t * chunk, hi = min(lo + chunk, N);
  int s = 0;
  for (int i = lo; i < hi; ++i) s += cnt[i];
  sums[t] = s; __syncthreads();
  for (int off = 1; off < 1024; off <<= 1){
    int v = 0;
    if (t >= off) v = sums[t - off];
    __syncthreads();
    if (t >= off) sums[t] += v;
    __syncthreads();
  }
  int pre = (t == 0) ? 0 : sums[t - 1];
  for (int i = lo; i < hi; ++i){ row_ptr[i] = pre; pre += cnt[i]; }
  if (t == 1023) row_ptr[N] = sums[1023];
}

__global__ __launch_bounds__(256) void k_copy(const int* __restrict__ a, int* __restrict__ b, int n){
  int i = blockIdx.x * 256 + threadIdx.x;
  if (i < n) b[i] = a[i];
}

__global__ __launch_bounds__(256) void k_fill(const void* __restrict__ ei, const float* __restrict__ ew, int E,
                                              const int* __restrict__ flag, int* __restrict__ cursor,
                                              int* __restrict__ csr_src, float* __restrict__ csr_ew){
  int e = blockIdx.x * 256 + threadIdx.x;
  if (e >= E) return;
  int src, dst;
  if (*flag){ src = ((const int*)ei)[e]; dst = ((const int*)ei)[(size_t)E + e]; }
  else      { src = (int)((const long long*)ei)[e]; dst = (int)((const long long*)ei)[(size_t)E + e]; }
  int pos = atomicAdd(&cursor[dst], 1);
  csr_src[pos] = src;
  csr_ew[pos] = ew[e];
}

__global__ __launch_bounds__(256) void k_degrees(const int* __restrict__ row_ptr, const float* __restrict__ csr_ew,
                                                 float* __restrict__ dis1, float* __restrict__ dis2,
                                                 float* __restrict__ invw, int N){
  int r = blockIdx.x * 256 + threadIdx.x;
  if (r >= N) return;
  int e0 = row_ptr[r], e1 = row_ptr[r + 1];
  float s = 0.f;
  for (int e = e0; e < e1; ++e) s += csr_ew[e];
  dis1[r] = rsqrtf(s + 1.0f);                      // GCN deg includes self-loop weight 1, always > 0
  dis2[r] = (s > 0.0f) ? rsqrtf(s) : 0.0f;         // Cheb: safe rsqrt
  invw[r] = 1.0f / (float)(e1 - e0 + 1);           // ClusterGCN: 1/(indeg+1)
}

// ---------------- fp32 tiled GEMM: C = A@B + dscale*D  (64x64x16, 4x4/thread) ----------------
__global__ __launch_bounds__(256) void k_gemm(const float* __restrict__ A, const float* __restrict__ B,
                                              const float* __restrict__ D, float dscale,
                                              float* __restrict__ C, int M, int Ncols, int K){
  __shared__ float As[16][68];
  __shared__ float Bs[16][68];
  int m0 = blockIdx.x * 64, n0 = blockIdx.y * 64;
  int t = threadIdx.x;
  int tx = t & 15, ty = t >> 4;
  int arow = t >> 2, acol = (t & 3) << 2;   // A tile: 64 rows x 16 k, float4 along k
  int brow = t >> 4, bcol = (t & 15) << 2;  // B tile: 16 k x 64 cols, float4 along n
  float acc[4][4] = {{0.f}};
  int arM = m0 + arow;
  const float* Aptr = A + (size_t)arM * K + acol;
  const float* Bptr = B + (size_t)brow * Ncols + n0 + bcol;
  for (int k0 = 0; k0 < K; k0 += 16){
    float4 av = make_float4(0.f, 0.f, 0.f, 0.f);
    if (arM < M) av = *(const float4*)(Aptr + k0);
    float4 bv = *(const float4*)(Bptr + (size_t)k0 * Ncols);
    As[acol + 0][arow] = av.x; As[acol + 1][arow] = av.y;
    As[acol + 2][arow] = av.z; As[acol + 3][arow] = av.w;
    *(float4*)&Bs[brow][bcol] = bv;
    __syncthreads();
#pragma unroll
    for (int k = 0; k < 16; ++k){
      float4 a = *(const float4*)&As[k][ty << 2];
      float4 b = *(const float4*)&Bs[k][tx << 2];
      float av4[4] = {a.x, a.y, a.z, a.w};
      float bv4[4] = {b.x, b.y, b.z, b.w};
#pragma unroll
      for (int i = 0; i < 4; ++i)
#pragma unroll
        for (int j = 0; j < 4; ++j)
          acc[i][j] = fmaf(av4[i], bv4[j], acc[i][j]);
    }
    __syncthreads();
  }
#pragma unroll
  for (int i = 0; i < 4; ++i){
    int m = m0 + (ty << 2) + i;
    if (m < M){
      size_t off = (size_t)m * Ncols + n0 + (tx << 2);
      float4 o = make_float4(acc[i][0], acc[i][1], acc[i][2], acc[i][3]);
      if (dscale != 0.f){
        float4 dv = *(const float4*)(D + off);
        o.x = fmaf(dscale, dv.x, o.x); o.y = fmaf(dscale, dv.y, o.y);
        o.z = fmaf(dscale, dv.z, o.z); o.w = fmaf(dscale, dv.w, o.w);
      }
      *(float4*)(C + off) = o;
    }
  }
}

// ---------------- GCN aggregation (width 256), wave per row, fused bias+relu ----------------
__global__ __launch_bounds__(256) void k_gcn_agg(const float* __restrict__ h0,
    const int* __restrict__ csr_src, const float* __restrict__ csr_ew,
    const int* __restrict__ row_ptr, const float* __restrict__ dis1,
    const float* __restrict__ b1, float* __restrict__ h1, int N){
  int lane = threadIdx.x & 63;
  int r = blockIdx.x * 4 + (threadIdx.x >> 6);
  if (r >= N) return;
  float dr = dis1[r];
  float4 self = ((const float4*)(h0 + (size_t)r * 256))[lane];
  float4 inner = make_float4(self.x * dr, self.y * dr, self.z * dr, self.w * dr); // self norm = dr*dr
  int e0 = row_ptr[r], e1 = row_ptr[r + 1];
  for (int e = e0; e < e1; ++e){
    int s = csr_src[e];
    float w = csr_ew[e] * dis1[s];
    float4 v = ((const float4*)(h0 + (size_t)s * 256))[lane];
    inner.x = fmaf(w, v.x, inner.x); inner.y = fmaf(w, v.y, inner.y);
    inner.z = fmaf(w, v.z, inner.z); inner.w = fmaf(w, v.w, inner.w);
  }
  float4 bb = ((const float4*)b1)[lane];
  float4 o;
  o.x = fmaxf(fmaf(inner.x, dr, bb.x), 0.f);
  o.y = fmaxf(fmaf(inner.y, dr, bb.y), 0.f);
  o.z = fmaxf(fmaf(inner.z, dr, bb.z), 0.f);
  o.w = fmaxf(fmaf(inner.w, dr, bb.w), 0.f);
  ((float4*)(h1 + (size_t)r * 256))[lane] = o;
}

// ---------------- Cheb spmm (width 128): out[r] += coef * dis2[r] * sum(ew*dis2[src]*b[src]) ----------------
__global__ __launch_bounds__(256) void k_cheb_spmm(const float* __restrict__ bsrc, float* __restrict__ out,
    const int* __restrict__ csr_src, const float* __restrict__ csr_ew,
    const int* __restrict__ row_ptr, const float* __restrict__ dis2, float coef, int N){
  int lane = threadIdx.x & 63;
  int r = blockIdx.x * 4 + (threadIdx.x >> 6);
  if (r >= N) return;
  float2 inner = make_float2(0.f, 0.f);
  int e0 = row_ptr[r], e1 = row_ptr[r + 1];
  for (int e = e0; e < e1; ++e){
    int s = csr_src[e];
    float w = csr_ew[e] * dis2[s];
    float2 v = ((const float2*)(bsrc + (size_t)s * 128))[lane];
    inner.x = fmaf(w, v.x, inner.x);
    inner.y = fmaf(w, v.y, inner.y);
  }
  float c = coef * dis2[r];
  float2* op = (float2*)(out + (size_t)r * 128) + lane;
  float2 cur = *op;
  cur.x = fmaf(c, inner.x, cur.x);
  cur.y = fmaf(c, inner.y, cur.y);
  *op = cur;
}

// ---------------- features epilogue: relu(P+bc) -> feat, p = h2.W_out, wr = h2.W_root ----------------
__global__ __launch_bounds__(256) void k_feat(const float* __restrict__ P, const float* __restrict__ bc,
    const float* __restrict__ W_out, const float* __restrict__ W_root,
    float* __restrict__ feat, float* __restrict__ p, float* __restrict__ wr, int N){
  int lane = threadIdx.x & 63;
  int r = blockIdx.x * 4 + (threadIdx.x >> 6);
  if (r >= N) return;
  float2 v = ((const float2*)(P + (size_t)r * 128))[lane];
  float2 bb = ((const float2*)bc)[lane];
  v.x = fmaxf(v.x + bb.x, 0.f);
  v.y = fmaxf(v.y + bb.y, 0.f);
  ((float2*)(feat + (size_t)r * 128))[lane] = v;
  float2 wo = ((const float2*)W_out)[lane];
  float2 wrt = ((const float2*)W_root)[lane];
  float pp = v.x * wo.x + v.y * wo.y;
  float rr = v.x * wrt.x + v.y * wrt.y;
#pragma unroll
  for (int off = 32; off; off >>= 1){
    pp += __shfl_xor(pp, off);
    rr += __shfl_xor(rr, off);
  }
  if (lane == 0){ p[r] = pp; wr[r] = rr; }
}

// ---------------- ClusterGCN output (width-1 spmm): out[r] = invw*(sum p[src]+p[r]) + wr[r] + b3 ----------------
__global__ __launch_bounds__(256) void k_out(const float* __restrict__ p, const float* __restrict__ wr,
    const float* __restrict__ invw, const int* __restrict__ csr_src, const int* __restrict__ row_ptr,
    const float* __restrict__ b3, float* __restrict__ out, int N){
  int r = blockIdx.x * 256 + threadIdx.x;
  if (r >= N) return;
  float s = p[r];
  int e0 = row_ptr[r], e1 = row_ptr[r + 1];
  for (int e = e0; e < e1; ++e) s += p[csr_src[e]];
  out[r] = invw[r] * s + wr[r] + b3[0];
}

extern "C" void kernel_launch(void* const* d_in, const int* in_sizes, int n_in,
                              void* d_out, int out_size, void* d_ws, size_t ws_size,
                              hipStream_t stream){
  const float* x      = (const float*)d_in[0];
  const void*  ei     = d_in[1];
  const float* ew     = (const float*)d_in[2];
  const float* W1     = (const float*)d_in[3];
  const float* b1     = (const float*)d_in[4];
  const float* Wc     = (const float*)d_in[5];
  const float* bc     = (const float*)d_in[6];
  const float* W_out  = (const float*)d_in[7];
  const float* W_root = (const float*)d_in[8];
  const float* b3     = (const float*)d_in[9];
  const int N = in_sizes[0] / 512;
  const int E = in_sizes[2];

  // workspace carve (all 256B-aligned)
  char* w = (char*)d_ws;
  auto alloc = [&](size_t bytes)->void*{ void* r = (void*)w; w += (bytes + 255) & ~(size_t)255; return r; };
  float* h0      = (float*)alloc((size_t)N * 256 * 4);   // GCN pre-agg; later P0/P1
  float* h1      = (float*)alloc((size_t)N * 256 * 4);   // GCN output (Cheb GEMM input)
  float* P2      = (float*)alloc((size_t)N * 128 * 4);
  float* csr_ew  = (float*)alloc((size_t)E * 4);
  int*   csr_src = (int*)  alloc((size_t)E * 4);
  int*   row_ptr = (int*)  alloc((size_t)(N + 1) * 4);
  int*   cursor  = (int*)  alloc((size_t)N * 4);
  int*   cnt     = (int*)  alloc((size_t)N * 4);
  float* dis1    = (float*)alloc((size_t)N * 4);
  float* dis2    = (float*)alloc((size_t)N * 4);
  float* invw    = (float*)alloc((size_t)N * 4);
  float* pbuf    = (float*)alloc((size_t)N * 4);
  float* wrbuf   = (float*)alloc((size_t)N * 4);
  int*   flag    = (int*)  alloc(256);
  float* P0 = h0;
  float* P1 = h0 + (size_t)N * 128;

  hipMemsetAsync(cnt, 0, (size_t)N * 4, stream);
  hipMemsetAsync(flag, 0, 4, stream);

  k_detect<<<16, 256, 0, stream>>>((const int*)ei, E, flag);
  k_count<<<ceil_div(E, 256), 256, 0, stream>>>(ei, E, flag, cnt);
  k_scan<<<1, 1024, 0, stream>>>(cnt, row_ptr, N);
  k_copy<<<ceil_div(N, 256), 256, 0, stream>>>(row_ptr, cursor, N);
  k_fill<<<ceil_div(E, 256), 256, 0, stream>>>(ei, ew, E, flag, cursor, csr_src, csr_ew);
  k_degrees<<<ceil_div(N, 256), 256, 0, stream>>>(row_ptr, csr_ew, dis1, dis2, invw, N);

  // ---- GCNConv: h0 = x@W1 ; h1 = relu(agg + b1) ----
  k_gemm<<<dim3(ceil_div(N, 64), 4), 256, 0, stream>>>(x, W1, nullptr, 0.f, h0, N, 256, 512);
  k_gcn_agg<<<ceil_div(N, 4), 256, 0, stream>>>(h0, csr_src, csr_ew, row_ptr, dis1, b1, h1, N);

  // ---- ChebConv via Clenshaw at width 128:
  //   b5 = C5; b4 = C4 + 2L b5; b3 = C3 - b5 + 2L b4; b2 = C2 - b4 + 2L b3;
  //   b1 = C1 - b3 + 2L b2; res = C0 - b2 + L b1.   (L = -(dis2*ew*dis2) -> coef -2 / -1)
  auto gemm2 = [&](int k, float* dst, const float* Dm, float ds){
    k_gemm<<<dim3(ceil_div(N, 64), 2), 256, 0, stream>>>(h1, Wc + (size_t)k * 256 * 128, Dm, ds, dst, N, 128, 256);
  };
  auto spmm = [&](float* dst, const float* src, float coef){
    k_cheb_spmm<<<ceil_div(N, 4), 256, 0, stream>>>(src, dst, csr_src, csr_ew, row_ptr, dis2, coef, N);
  };
  gemm2(5, P0, nullptr, 0.f);
  gemm2(4, P1, nullptr, 0.f);  spmm(P1, P0, -2.f);
  gemm2(3, P2, P0, -1.f);      spmm(P2, P1, -2.f);
  gemm2(2, P0, P1, -1.f);      spmm(P0, P2, -2.f);
  gemm2(1, P1, P2, -1.f);      spmm(P1, P0, -2.f);
  gemm2(0, P2, P0, -1.f);      spmm(P2, P1, -1.f);

  // ---- epilogue: features + ClusterGCN ----
  float* out  = (float*)d_out;
  float* feat = out + N;
  k_feat<<<ceil_div(N, 4), 256, 0, stream>>>(P2, bc, W_out, W_root, feat, pbuf, wrbuf, N);
  k_out<<<ceil_div(N, 256), 256, 0, stream>>>(pbuf, wrbuf, invw, csr_src, row_ptr, b3, out, N);
}

// Round 3
// 1971.462 us; speedup vs baseline: 1.2432x; 1.2432x over previous
//
#include <hip/hip_runtime.h>
#include <cstdint>
#include <cstddef>

typedef __attribute__((ext_vector_type(8))) short bf16x8;
typedef __attribute__((ext_vector_type(4))) float f32x4;

static inline int ceil_div(int a, int b){ return (a + b - 1) / b; }

struct HL { short h, l; };
__device__ inline HL split2(float a){
  unsigned u = __float_as_uint(a);
  unsigned hb = (u + 0x8000u) & 0xFFFF0000u;   // round-to-nearest-ish bf16 high part
  float r = a - __uint_as_float(hb);           // exact (nearby subtraction)
  HL o;
  o.h = (short)(hb >> 16);
  o.l = (short)((__float_as_uint(r) + 0x8000u) >> 16);
  return o;
}

// ---------------- dtype detection (int64 vs int32 edge_index) ----------------
__global__ __launch_bounds__(256) void k_detect(const int* __restrict__ ei32, int E, int* __restrict__ flag){
  int t = blockIdx.x * 256 + threadIdx.x;
  if (t < 4096) {
    long long idx = 2LL * t + 1;
    if (idx < 2LL * E && ei32[idx] != 0) atomicOr(flag, 1);
  }
}

// ---------------- CSR build ----------------
__global__ __launch_bounds__(256) void k_count(const void* __restrict__ ei, int E,
                                               const int* __restrict__ flag, int* __restrict__ cnt){
  int e = blockIdx.x * 256 + threadIdx.x;
  if (e >= E) return;
  int dst = (*flag) ? ((const int*)ei)[(size_t)E + e]
                    : (int)((const long long*)ei)[(size_t)E + e];
  atomicAdd(&cnt[dst], 1);
}

__global__ __launch_bounds__(1024) void k_scan(const int* __restrict__ cnt, int* __restrict__ row_ptr, int N){
  __shared__ int sums[1024];
  int t = threadIdx.x;
  int chunk = (N + 1023) >> 10;
  int lo = t * chunk, hi = min(lo + chunk, N);
  int s = 0;
  for (int i = lo; i < hi; ++i) s += cnt[i];
  sums[t] = s; __syncthreads();
  for (int off = 1; off < 1024; off <<= 1){
    int v = 0;
    if (t >= off) v = sums[t - off];
    __syncthreads();
    if (t >= off) sums[t] += v;
    __syncthreads();
  }
  int pre = (t == 0) ? 0 : sums[t - 1];
  for (int i = lo; i < hi; ++i){ row_ptr[i] = pre; pre += cnt[i]; }
  if (t == 1023) row_ptr[N] = sums[1023];
}

__global__ __launch_bounds__(256) void k_copy(const int* __restrict__ a, int* __restrict__ b, int n){
  int i = blockIdx.x * 256 + threadIdx.x;
  if (i < n) b[i] = a[i];
}

__global__ __launch_bounds__(256) void k_fill(const void* __restrict__ ei, const float* __restrict__ ew, int E,
                                              const int* __restrict__ flag, int* __restrict__ cursor,
                                              int* __restrict__ csr_src, float* __restrict__ csr_ew){
  int e = blockIdx.x * 256 + threadIdx.x;
  if (e >= E) return;
  int src, dst;
  if (*flag){ src = ((const int*)ei)[e]; dst = ((const int*)ei)[(size_t)E + e]; }
  else      { src = (int)((const long long*)ei)[e]; dst = (int)((const long long*)ei)[(size_t)E + e]; }
  int pos = atomicAdd(&cursor[dst], 1);
  csr_src[pos] = src;
  csr_ew[pos] = ew[e];
}

__global__ __launch_bounds__(256) void k_degrees(const int* __restrict__ row_ptr, const float* __restrict__ csr_ew,
                                                 float* __restrict__ dis1, float* __restrict__ dis2,
                                                 float* __restrict__ invw, int N){
  int r = blockIdx.x * 256 + threadIdx.x;
  if (r >= N) return;
  int e0 = row_ptr[r], e1 = row_ptr[r + 1];
  float s = 0.f;
  for (int e = e0; e < e1; ++e) s += csr_ew[e];
  dis1[r] = rsqrtf(s + 1.0f);
  dis2[r] = (s > 0.0f) ? rsqrtf(s) : 0.0f;
  invw[r] = 1.0f / (float)(e1 - e0 + 1);
}

// ---------------- weight prep: W [K][N] fp32 -> Wh/Wl [N][K] bf16 split ----------------
__global__ __launch_bounds__(256) void k_prep_w(const float* __restrict__ W, short* __restrict__ Wh,
                                                short* __restrict__ Wl, int K, int N){
  int idx = blockIdx.x * 256 + threadIdx.x;
  if (idx >= K * N) return;
  int n = idx / K, k = idx - n * K;
  HL s = split2(W[(size_t)k * N + n]);
  Wh[idx] = s.h; Wl[idx] = s.l;
}

// ---------------- MFMA GEMM: C = A@B + dscale*D, A fp32 [M][K] (split on the fly),
// ---------------- B pre-split/transposed [N][K] bf16.  128x128 tile, BK=32, 4 waves.
__global__ __launch_bounds__(256) void k_gemm_mfma(
    const float* __restrict__ A,
    const short* __restrict__ Bh, const short* __restrict__ Bl,
    const float* __restrict__ D, float dscale,
    float* __restrict__ C, int M, int Ncols, int K)
{
  __shared__ short Ah[128][40];
  __shared__ short Al[128][40];
  __shared__ short Bhs[128][40];
  __shared__ short Bls[128][40];
  int m0 = blockIdx.x * 128, n0 = blockIdx.y * 128;
  int t = threadIdx.x;
  int lane = t & 63, wid = t >> 6;
  int wr = wid >> 1, wc = wid & 1;
  int fr = lane & 15, fq = lane >> 4;
  int srow = t >> 1, skh = (t & 1) << 4;     // staging: row 0..127, k-offset 0/16

  f32x4 acc[4][4];
#pragma unroll
  for (int i = 0; i < 4; ++i)
#pragma unroll
    for (int j = 0; j < 4; ++j) acc[i][j] = (f32x4){0.f, 0.f, 0.f, 0.f};

  bool aval = (m0 + srow) < M;
  const float* Aptr = A + (size_t)(m0 + srow) * K + skh;
  const short* Bhp = Bh + (size_t)(n0 + srow) * K + skh;
  const short* Blp = Bl + (size_t)(n0 + srow) * K + skh;

  for (int k0 = 0; k0 < K; k0 += 32){
    __syncthreads();
    // ---- stage A: 16 fp32 per thread -> split bf16 ----
    float av[16];
    if (aval){
      const float4* ap = (const float4*)(Aptr + k0);
      float4 a0 = ap[0], a1 = ap[1], a2 = ap[2], a3 = ap[3];
      av[0]=a0.x; av[1]=a0.y; av[2]=a0.z; av[3]=a0.w;
      av[4]=a1.x; av[5]=a1.y; av[6]=a1.z; av[7]=a1.w;
      av[8]=a2.x; av[9]=a2.y; av[10]=a2.z; av[11]=a2.w;
      av[12]=a3.x; av[13]=a3.y; av[14]=a3.z; av[15]=a3.w;
    } else {
#pragma unroll
      for (int i = 0; i < 16; ++i) av[i] = 0.f;
    }
    bf16x8 h0, h1, l0, l1;
#pragma unroll
    for (int i = 0; i < 8; ++i){
      HL s = split2(av[i]);
      h0[i] = s.h; l0[i] = s.l;
    }
#pragma unroll
    for (int i = 0; i < 8; ++i){
      HL s = split2(av[8 + i]);
      h1[i] = s.h; l1[i] = s.l;
    }
    *(bf16x8*)&Ah[srow][skh]     = h0;
    *(bf16x8*)&Ah[srow][skh + 8] = h1;
    *(bf16x8*)&Al[srow][skh]     = l0;
    *(bf16x8*)&Al[srow][skh + 8] = l1;
    // ---- stage B: straight bf16 copies ----
    {
      const bf16x8* bp = (const bf16x8*)(Bhp + k0);
      *(bf16x8*)&Bhs[srow][skh]     = bp[0];
      *(bf16x8*)&Bhs[srow][skh + 8] = bp[1];
      const bf16x8* cp = (const bf16x8*)(Blp + k0);
      *(bf16x8*)&Bls[srow][skh]     = cp[0];
      *(bf16x8*)&Bls[srow][skh + 8] = cp[1];
    }
    __syncthreads();
    // ---- fragments + MFMA ----
    bf16x8 afh[4], afl[4], bfh[4], bfl[4];
#pragma unroll
    for (int m = 0; m < 4; ++m){
      int r = wr * 64 + m * 16 + fr;
      afh[m] = *(const bf16x8*)&Ah[r][fq * 8];
      afl[m] = *(const bf16x8*)&Al[r][fq * 8];
    }
#pragma unroll
    for (int n = 0; n < 4; ++n){
      int r = wc * 64 + n * 16 + fr;
      bfh[n] = *(const bf16x8*)&Bhs[r][fq * 8];
      bfl[n] = *(const bf16x8*)&Bls[r][fq * 8];
    }
#pragma unroll
    for (int m = 0; m < 4; ++m)
#pragma unroll
      for (int n = 0; n < 4; ++n){
        acc[m][n] = __builtin_amdgcn_mfma_f32_16x16x32_bf16(afh[m], bfh[n], acc[m][n], 0, 0, 0);
        acc[m][n] = __builtin_amdgcn_mfma_f32_16x16x32_bf16(afl[m], bfh[n], acc[m][n], 0, 0, 0);
        acc[m][n] = __builtin_amdgcn_mfma_f32_16x16x32_bf16(afh[m], bfl[n], acc[m][n], 0, 0, 0);
      }
  }
  // ---- epilogue: C = acc + dscale*D ----
#pragma unroll
  for (int m = 0; m < 4; ++m){
#pragma unroll
    for (int n = 0; n < 4; ++n){
      int col = n0 + wc * 64 + n * 16 + fr;
#pragma unroll
      for (int r = 0; r < 4; ++r){
        int row = m0 + wr * 64 + m * 16 + fq * 4 + r;
        if (row < M){
          size_t off = (size_t)row * Ncols + col;
          float v = acc[m][n][r];
          if (dscale != 0.f) v = fmaf(dscale, D[off], v);
          C[off] = v;
        }
      }
    }
  }
}

// ---------------- GCN aggregation (width 256), wave per row, fused bias+relu ----------------
__global__ __launch_bounds__(256) void k_gcn_agg(const float* __restrict__ h0,
    const int* __restrict__ csr_src, const float* __restrict__ csr_ew,
    const int* __restrict__ row_ptr, const float* __restrict__ dis1,
    const float* __restrict__ b1, float* __restrict__ h1, int N){
  int lane = threadIdx.x & 63;
  int r = blockIdx.x * 4 + (threadIdx.x >> 6);
  if (r >= N) return;
  float dr = dis1[r];
  float4 self = ((const float4*)(h0 + (size_t)r * 256))[lane];
  float4 inner = make_float4(self.x * dr, self.y * dr, self.z * dr, self.w * dr);
  int e0 = row_ptr[r], e1 = row_ptr[r + 1];
  for (int e = e0; e < e1; ++e){
    int s = csr_src[e];
    float w = csr_ew[e] * dis1[s];
    float4 v = ((const float4*)(h0 + (size_t)s * 256))[lane];
    inner.x = fmaf(w, v.x, inner.x); inner.y = fmaf(w, v.y, inner.y);
    inner.z = fmaf(w, v.z, inner.z); inner.w = fmaf(w, v.w, inner.w);
  }
  float4 bb = ((const float4*)b1)[lane];
  float4 o;
  o.x = fmaxf(fmaf(inner.x, dr, bb.x), 0.f);
  o.y = fmaxf(fmaf(inner.y, dr, bb.y), 0.f);
  o.z = fmaxf(fmaf(inner.z, dr, bb.z), 0.f);
  o.w = fmaxf(fmaf(inner.w, dr, bb.w), 0.f);
  ((float4*)(h1 + (size_t)r * 256))[lane] = o;
}

// ---------------- Cheb spmm (width 128) ----------------
__global__ __launch_bounds__(256) void k_cheb_spmm(const float* __restrict__ bsrc, float* __restrict__ out,
    const int* __restrict__ csr_src, const float* __restrict__ csr_ew,
    const int* __restrict__ row_ptr, const float* __restrict__ dis2, float coef, int N){
  int lane = threadIdx.x & 63;
  int r = blockIdx.x * 4 + (threadIdx.x >> 6);
  if (r >= N) return;
  float2 inner = make_float2(0.f, 0.f);
  int e0 = row_ptr[r], e1 = row_ptr[r + 1];
  for (int e = e0; e < e1; ++e){
    int s = csr_src[e];
    float w = csr_ew[e] * dis2[s];
    float2 v = ((const float2*)(bsrc + (size_t)s * 128))[lane];
    inner.x = fmaf(w, v.x, inner.x);
    inner.y = fmaf(w, v.y, inner.y);
  }
  float c = coef * dis2[r];
  float2* op = (float2*)(out + (size_t)r * 128) + lane;
  float2 cur = *op;
  cur.x = fmaf(c, inner.x, cur.x);
  cur.y = fmaf(c, inner.y, cur.y);
  *op = cur;
}

// ---------------- features epilogue ----------------
__global__ __launch_bounds__(256) void k_feat(const float* __restrict__ P, const float* __restrict__ bc,
    const float* __restrict__ W_out, const float* __restrict__ W_root,
    float* __restrict__ feat, float* __restrict__ p, float* __restrict__ wr, int N){
  int lane = threadIdx.x & 63;
  int r = blockIdx.x * 4 + (threadIdx.x >> 6);
  if (r >= N) return;
  float2 v = ((const float2*)(P + (size_t)r * 128))[lane];
  float2 bb = ((const float2*)bc)[lane];
  v.x = fmaxf(v.x + bb.x, 0.f);
  v.y = fmaxf(v.y + bb.y, 0.f);
  ((float2*)(feat + (size_t)r * 128))[lane] = v;
  float2 wo = ((const float2*)W_out)[lane];
  float2 wrt = ((const float2*)W_root)[lane];
  float pp = v.x * wo.x + v.y * wo.y;
  float rr = v.x * wrt.x + v.y * wrt.y;
#pragma unroll
  for (int off = 32; off; off >>= 1){
    pp += __shfl_xor(pp, off);
    rr += __shfl_xor(rr, off);
  }
  if (lane == 0){ p[r] = pp; wr[r] = rr; }
}

// ---------------- ClusterGCN output ----------------
__global__ __launch_bounds__(256) void k_out(const float* __restrict__ p, const float* __restrict__ wr,
    const float* __restrict__ invw, const int* __restrict__ csr_src, const int* __restrict__ row_ptr,
    const float* __restrict__ b3, float* __restrict__ out, int N){
  int r = blockIdx.x * 256 + threadIdx.x;
  if (r >= N) return;
  float s = p[r];
  int e0 = row_ptr[r], e1 = row_ptr[r + 1];
  for (int e = e0; e < e1; ++e) s += p[csr_src[e]];
  out[r] = invw[r] * s + wr[r] + b3[0];
}

extern "C" void kernel_launch(void* const* d_in, const int* in_sizes, int n_in,
                              void* d_out, int out_size, void* d_ws, size_t ws_size,
                              hipStream_t stream){
  const float* x      = (const float*)d_in[0];
  const void*  ei     = d_in[1];
  const float* ew     = (const float*)d_in[2];
  const float* W1     = (const float*)d_in[3];
  const float* b1     = (const float*)d_in[4];
  const float* Wc     = (const float*)d_in[5];
  const float* bc     = (const float*)d_in[6];
  const float* W_out  = (const float*)d_in[7];
  const float* W_root = (const float*)d_in[8];
  const float* b3     = (const float*)d_in[9];
  const int N = in_sizes[0] / 512;
  const int E = in_sizes[2];

  char* w = (char*)d_ws;
  auto alloc = [&](size_t bytes)->void*{ void* r = (void*)w; w += (bytes + 255) & ~(size_t)255; return r; };
  float* h0      = (float*)alloc((size_t)N * 256 * 4);   // x@W1; later P0/P1
  float* h1      = (float*)alloc((size_t)N * 256 * 4);   // GCN output (Cheb GEMM A)
  float* P2      = (float*)alloc((size_t)N * 128 * 4);
  float* csr_ew  = (float*)alloc((size_t)E * 4);
  int*   csr_src = (int*)  alloc((size_t)E * 4);
  int*   row_ptr = (int*)  alloc((size_t)(N + 1) * 4);
  int*   cursor  = (int*)  alloc((size_t)N * 4);
  int*   cnt     = (int*)  alloc((size_t)N * 4);
  float* dis1    = (float*)alloc((size_t)N * 4);
  float* dis2    = (float*)alloc((size_t)N * 4);
  float* invw    = (float*)alloc((size_t)N * 4);
  float* pbuf    = (float*)alloc((size_t)N * 4);
  float* wrbuf   = (float*)alloc((size_t)N * 4);
  short* W1t_h   = (short*)alloc((size_t)512 * 256 * 2);
  short* W1t_l   = (short*)alloc((size_t)512 * 256 * 2);
  short* Wct_h   = (short*)alloc((size_t)6 * 256 * 128 * 2);
  short* Wct_l   = (short*)alloc((size_t)6 * 256 * 128 * 2);
  int*   flag    = (int*)  alloc(256);
  float* P0 = h0;
  float* P1 = h0 + (size_t)N * 128;

  hipMemsetAsync(cnt, 0, (size_t)N * 4, stream);
  hipMemsetAsync(flag, 0, 4, stream);

  k_detect<<<16, 256, 0, stream>>>((const int*)ei, E, flag);
  k_count<<<ceil_div(E, 256), 256, 0, stream>>>(ei, E, flag, cnt);
  k_scan<<<1, 1024, 0, stream>>>(cnt, row_ptr, N);
  k_copy<<<ceil_div(N, 256), 256, 0, stream>>>(row_ptr, cursor, N);
  k_fill<<<ceil_div(E, 256), 256, 0, stream>>>(ei, ew, E, flag, cursor, csr_src, csr_ew);
  k_degrees<<<ceil_div(N, 256), 256, 0, stream>>>(row_ptr, csr_ew, dis1, dis2, invw, N);

  // weight prep (transpose + bf16 split)
  k_prep_w<<<ceil_div(512 * 256, 256), 256, 0, stream>>>(W1, W1t_h, W1t_l, 512, 256);
  for (int k = 0; k < 6; ++k)
    k_prep_w<<<ceil_div(256 * 128, 256), 256, 0, stream>>>(Wc + (size_t)k * 256 * 128,
        Wct_h + (size_t)k * 256 * 128, Wct_l + (size_t)k * 256 * 128, 256, 128);

  // ---- GCNConv ----
  k_gemm_mfma<<<dim3(ceil_div(N, 128), 2), 256, 0, stream>>>(x, W1t_h, W1t_l, nullptr, 0.f, h0, N, 256, 512);
  k_gcn_agg<<<ceil_div(N, 4), 256, 0, stream>>>(h0, csr_src, csr_ew, row_ptr, dis1, b1, h1, N);

  // ---- ChebConv via Clenshaw (width 128) ----
  auto gemm2 = [&](int k, float* dst, const float* Dm, float ds){
    k_gemm_mfma<<<dim3(ceil_div(N, 128), 1), 256, 0, stream>>>(h1,
        Wct_h + (size_t)k * 256 * 128, Wct_l + (size_t)k * 256 * 128, Dm, ds, dst, N, 128, 256);
  };
  auto spmm = [&](float* dst, const float* src, float coef){
    k_cheb_spmm<<<ceil_div(N, 4), 256, 0, stream>>>(src, dst, csr_src, csr_ew, row_ptr, dis2, coef, N);
  };
  gemm2(5, P0, nullptr, 0.f);
  gemm2(4, P1, nullptr, 0.f);  spmm(P1, P0, -2.f);
  gemm2(3, P2, P0, -1.f);      spmm(P2, P1, -2.f);
  gemm2(2, P0, P1, -1.f);      spmm(P0, P2, -2.f);
  gemm2(1, P1, P2, -1.f);      spmm(P1, P0, -2.f);
  gemm2(0, P2, P0, -1.f);      spmm(P2, P1, -1.f);

  // ---- epilogue ----
  float* out  = (float*)d_out;
  float* feat = out + N;
  k_feat<<<ceil_div(N, 4), 256, 0, stream>>>(P2, bc, W_out, W_root, feat, pbuf, wrbuf, N);
  k_out<<<ceil_div(N, 256), 256, 0, stream>>>(pbuf, wrbuf, invw, csr_src, row_ptr, b3, out, N);
}